// Round 16
// baseline (4570.421 us; speedup 1.0000x reference)
//
#include <hip/hip_runtime.h>
#include <hip/hip_bf16.h>
#include <math.h>

#define BATCH 2
#define LSEQ 577
#define DM 1024
#define DI 2048
#define DSTATE 16
#define DTR 64
#define NLAYERS 24
#define NP 576
#define MROWS 1154
#define NC 32
#define LC 19
#define LOG2E 1.4426950408889634f

typedef __attribute__((ext_vector_type(8))) short short8v;
typedef __attribute__((ext_vector_type(4))) float f32x4;

__device__ __forceinline__ ushort f2bf(float f) {
  unsigned int b = __float_as_uint(f);
  return (ushort)((b + 0x7FFFu + ((b >> 16) & 1u)) >> 16);
}
__device__ __forceinline__ float bf2f(ushort u) {
  return __uint_as_float(((unsigned int)u) << 16);
}
__device__ __forceinline__ void gload16(const void* g, void* l) {
  __builtin_amdgcn_global_load_lds(
      (const __attribute__((address_space(1))) unsigned int*)g,
      (__attribute__((address_space(3))) unsigned int*)l, 16, 0, 0);
}
__device__ __forceinline__ void cvt16(const float* g, char* ldsrow, int bb, int bswz) {
  float4 v0 = *(const float4*)(g);
  float4 v1 = *(const float4*)(g + 4);
  float4 v2 = *(const float4*)(g + 8);
  float4 v3 = *(const float4*)(g + 12);
  short8v c0 = {(short)f2bf(v0.x), (short)f2bf(v0.y), (short)f2bf(v0.z), (short)f2bf(v0.w),
                (short)f2bf(v1.x), (short)f2bf(v1.y), (short)f2bf(v1.z), (short)f2bf(v1.w)};
  short8v c1 = {(short)f2bf(v2.x), (short)f2bf(v2.y), (short)f2bf(v2.z), (short)f2bf(v2.w),
                (short)f2bf(v3.x), (short)f2bf(v3.y), (short)f2bf(v3.z), (short)f2bf(v3.w)};
  *(short8v*)(ldsrow + (bb ^ bswz)) = c0;
  *(short8v*)(ldsrow + ((bb + 16) ^ bswz)) = c1;
}

// ------- fp32 -> bf16 conversion: ONLY patch + xproj + dt weights (35 MB) -------
#define SEG0 786432u     // patch 1024*768
#define SEG1 4718592u    // xp 24*96*2048
#define SEG2 3145728u    // dt 24*2048*64
#define CUM1 (SEG0)
#define CUM2 (CUM1+SEG1)
#define CUMT (CUM2+SEG2)
#define F2BF_BLOCKS (CUMT/4096)   // 2112

__global__ void f2bf_all_k(const float* __restrict__ i0, const float* __restrict__ i1,
                           const float* __restrict__ i2,
                           ushort* __restrict__ o0, ushort* __restrict__ o1,
                           ushort* __restrict__ o2) {
  size_t base = (size_t)blockIdx.x * 4096;
  const float* in; ushort* out; size_t off;
  if (base < CUM1)      { in = i0; out = o0; off = base; }
  else if (base < CUM2) { in = i1; out = o1; off = base - CUM1; }
  else                  { in = i2; out = o2; off = base - CUM2; }
  size_t p = off + threadIdx.x * 4;
  #pragma unroll
  for (int j = 0; j < 4; ++j) {
    float4 v = *(const float4*)(in + p + j * 1024);
    ushort4 o;
    o.x = f2bf(v.x); o.y = f2bf(v.y); o.z = f2bf(v.z); o.w = f2bf(v.w);
    *(ushort4*)(out + p + j * 1024) = o;
  }
}

// ======================= 64x128 bf16 MFMA GEMM =======================
// A: bf16 via gload_lds (AF32=0) or fp32 reg-staged (AF32=1, dt only).
// B: bf16 via gload_lds (BF32=0) or fp32 reg-staged + in-reg cvt + swizzled
//    ds_write (BF32=1, in/out proj — skips the weight-conversion prologue).
// BF32 pipeline: stageA(k+1)+loadB(k+1) issued BEFORE MFMA(k); cvt+write after.
// MODE 1: C+=v  3: patch scatter  4: xc/z bf16 split  5: softplus->bf16 (dt)
template<int AF32, int BF32, int MODE>
__global__ __launch_bounds__(256) void gemm64(
    const void* __restrict__ Ap_, int lda,
    const void* __restrict__ Bw_, int ldb,
    float* __restrict__ C, int ldc,
    int M, int N, int K,
    const float* __restrict__ bias, const float* __restrict__ pos,
    ushort* __restrict__ o16a, ushort* __restrict__ o16b)
{
  __shared__ char lds[AF32 ? 24576 : 49152];
  int tid = threadIdx.x;
  int lane = tid & 63, w = tid >> 6;

  int nwg = gridDim.x * gridDim.y;
  int f = blockIdx.y * gridDim.x + blockIdx.x;
  int L = (f & 7) * (nwg >> 3) + (f >> 3);
  int bx = L % gridDim.x, by = L / gridDim.x;
  int bm = by * 64, bn = bx * 128;

  int srow = tid >> 3;
  int scol = ((tid & 7) ^ (srow & 7)) << 3;

  // bf16-B staging pointers (BF32=0)
  const ushort* gb0 = nullptr; const ushort* gb1 = nullptr;
  const ushort* gb2 = nullptr; const ushort* gb3 = nullptr;
  // fp32-B staging (BF32=1): thread t -> row tid>>1, 32 elems at (tid&1)*32
  const float* gBf = nullptr; int brow32 = 0, bhalf = 0, bswzB = 0;
  if constexpr (!BF32) {
    const ushort* Bw = (const ushort*)Bw_;
    gb0 = Bw + (size_t)(bn + srow) * ldb + scol;
    gb1 = Bw + (size_t)(bn + 32 + srow) * ldb + scol;
    gb2 = Bw + (size_t)(bn + 64 + srow) * ldb + scol;
    gb3 = Bw + (size_t)(bn + 96 + srow) * ldb + scol;
  } else {
    brow32 = tid >> 1; bhalf = tid & 1; bswzB = (brow32 & 7) << 4;
    gBf = (const float*)Bw_ + (size_t)(bn + brow32) * ldb + bhalf * 32;
  }

  const ushort* ga0 = nullptr; const ushort* ga1 = nullptr;
  const float* gAf = nullptr; char* ldsArow = nullptr; int bb = 0, bswz = 0;
  if (!AF32) {
    const ushort* Abf = (const ushort*)Ap_;
    int ra0 = bm + srow;      if (ra0 > M - 1) ra0 = M - 1;
    int ra1 = bm + 32 + srow; if (ra1 > M - 1) ra1 = M - 1;
    ga0 = Abf + (size_t)ra0 * lda + scol;
    ga1 = Abf + (size_t)ra1 * lda + scol;
  } else {
    int brow = tid >> 2;
    int be0 = (tid & 3) << 4;
    bb = be0 << 1; bswz = (brow & 7) << 4;
    int raf = bm + brow; if (raf > M - 1) raf = M - 1;
    gAf = (const float*)Ap_ + (size_t)raf * lda + be0;
    ldsArow = lds + brow * 128;
  }

  int wr = w >> 1, wc = w & 1;
  int fr = lane & 15;
  int fsw = (fr & 7) << 4;
  int fk = (lane >> 4) << 4;

  f32x4 acc[2][4];
  #pragma unroll
  for (int m = 0; m < 2; ++m)
    #pragma unroll
    for (int n = 0; n < 4; ++n) acc[m][n] = (f32x4){0.f, 0.f, 0.f, 0.f};

  #define MFMA_STEP(p)                                                          \
    _Pragma("unroll")                                                           \
    for (int ks = 0; ks < 2; ++ks) {                                            \
      int cb = (ks * 64 + fk) ^ fsw;                                            \
      short8v af[2], bf[4];                                                     \
      _Pragma("unroll")                                                         \
      for (int m = 0; m < 2; ++m)                                               \
        af[m] = *(const short8v*)((p) + (wr * 32 + m * 16 + fr) * 128 + cb);    \
      _Pragma("unroll")                                                         \
      for (int n = 0; n < 4; ++n)                                               \
        bf[n] = *(const short8v*)((p) + 8192 + (wc * 64 + n * 16 + fr) * 128 + cb); \
      _Pragma("unroll")                                                         \
      for (int m = 0; m < 2; ++m)                                               \
        _Pragma("unroll")                                                       \
        for (int n = 0; n < 4; ++n)                                             \
          acc[m][n] = __builtin_amdgcn_mfma_f32_16x16x32_bf16(af[m], bf[n], acc[m][n], 0, 0, 0); \
    }

  if constexpr (BF32) {
    float4 rb[8];
    auto stageA = [&](int buf, int k0) {
      char* p = lds + buf * 24576;
      gload16(ga0 + k0, p + (w << 10));
      gload16(ga1 + k0, p + 4096 + (w << 10));
    };
    auto loadB = [&](int k0) {
      #pragma unroll
      for (int j = 0; j < 8; ++j) rb[j] = *(const float4*)(gBf + k0 + j * 4);
    };
    auto writeB = [&](int buf) {
      char* prow = lds + buf * 24576 + 8192 + brow32 * 128;
      int bb0 = bhalf * 64;
      #pragma unroll
      for (int j = 0; j < 4; ++j) {
        float4 v0 = rb[2 * j], v1 = rb[2 * j + 1];
        short8v c = {(short)f2bf(v0.x), (short)f2bf(v0.y), (short)f2bf(v0.z), (short)f2bf(v0.w),
                     (short)f2bf(v1.x), (short)f2bf(v1.y), (short)f2bf(v1.z), (short)f2bf(v1.w)};
        *(short8v*)(prow + ((bb0 + j * 16) ^ bswzB)) = c;
      }
    };
    int nk = K >> 6;
    stageA(0, 0);
    loadB(0);
    writeB(0);
    __syncthreads();
    for (int k = 0; k < nk; ++k) {
      int cur = k & 1;
      if (k + 1 < nk) { stageA(cur ^ 1, (k + 1) << 6); loadB((k + 1) << 6); }
      char* p = lds + cur * 24576;
      MFMA_STEP(p)
      if (k + 1 < nk) writeB(cur ^ 1);
      __syncthreads();
    }
  } else if constexpr (!AF32) {
    auto stage = [&](int buf, int k0) {
      char* p = lds + buf * 24576;
      gload16(ga0 + k0, p + (w << 10));
      gload16(ga1 + k0, p + 4096 + (w << 10));
      gload16(gb0 + k0, p + 8192 + (w << 10));
      gload16(gb1 + k0, p + 12288 + (w << 10));
      gload16(gb2 + k0, p + 16384 + (w << 10));
      gload16(gb3 + k0, p + 20480 + (w << 10));
    };
    int nk = K >> 6;
    stage(0, 0);
    for (int k = 0; k < nk; ++k) {
      int cur = k & 1;
      if (k + 1 < nk) {
        stage(cur ^ 1, (k + 1) << 6);
        asm volatile("s_waitcnt vmcnt(6)" ::: "memory");
      } else {
        asm volatile("s_waitcnt vmcnt(0)" ::: "memory");
      }
      __builtin_amdgcn_s_barrier();
      char* p = lds + cur * 24576;
      MFMA_STEP(p)
      __builtin_amdgcn_s_barrier();
    }
  } else {
    for (int k0 = 0; k0 < K; k0 += 64) {
      cvt16(gAf + k0, ldsArow, bb, bswz);
      gload16(gb0 + k0, lds + 8192 + (w << 10));
      gload16(gb1 + k0, lds + 12288 + (w << 10));
      gload16(gb2 + k0, lds + 16384 + (w << 10));
      gload16(gb3 + k0, lds + 20480 + (w << 10));
      __syncthreads();
      char* p = lds;
      MFMA_STEP(p)
      __syncthreads();
    }
  }
  #undef MFMA_STEP

  #pragma unroll
  for (int m = 0; m < 2; ++m) {
    int rb2 = bm + wr * 32 + m * 16 + ((lane >> 4) << 2);
    #pragma unroll
    for (int j = 0; j < 4; ++j) {
      int r = rb2 + j;
      if (r >= M) break;
      #pragma unroll
      for (int n2 = 0; n2 < 4; ++n2) {
        int n = bn + wc * 64 + n2 * 16 + fr;
        float v = acc[m][n2][j];
        if (MODE == 1) {
          C[(size_t)r * ldc + n] += v;
        } else if (MODE == 3) {
          int b = r / NP, p = r % NP;
          C[((size_t)(b * LSEQ + 1 + p)) * ldc + n] = v + bias[n] + pos[(size_t)(1 + p) * ldc + n];
        } else if (MODE == 4) {
          if (n < DI) o16a[(size_t)r * DI + n] = f2bf(v);
          else        o16b[(size_t)r * DI + n - DI] = f2bf(v);
        } else {
          float t = v + bias[n];
          o16a[(size_t)r * N + n] = f2bf((t > 20.f) ? t : log1pf(__expf(t)));
        }
      }
    }
  }
}

// ======================= x_proj split-K MFMA (dbuf + counted vmcnt) ==========
__global__ __launch_bounds__(256) void xproj_k(
    const ushort* __restrict__ A, const ushort* __restrict__ W,
    float* __restrict__ C, int M)
{
  __shared__ char lds[40960];
  int tid = threadIdx.x;
  int lane = tid & 63, w = tid >> 6;
  int bm = blockIdx.y * 64;
  int kbase = blockIdx.x * 256;

  int srow = tid >> 3;
  int scol = ((tid & 7) ^ (srow & 7)) << 3;
  int ra0 = bm + srow;      if (ra0 > M - 1) ra0 = M - 1;
  int ra1 = bm + 32 + srow; if (ra1 > M - 1) ra1 = M - 1;
  const ushort* ga0 = A + (size_t)ra0 * DI + kbase + scol;
  const ushort* ga1 = A + (size_t)ra1 * DI + kbase + scol;
  const ushort* gb0 = W + (size_t)(srow)      * DI + kbase + scol;
  const ushort* gb1 = W + (size_t)(srow + 32) * DI + kbase + scol;
  const ushort* gb2 = W + (size_t)(srow + 64) * DI + kbase + scol;

  int fr = lane & 15;
  int fsw = (fr & 7) << 4;
  int fk = (lane >> 4) << 4;
  int arow = (w * 16 + fr) * 128;

  f32x4 acc[6];
  #pragma unroll
  for (int n = 0; n < 6; ++n) acc[n] = (f32x4){0.f, 0.f, 0.f, 0.f};

  auto stage = [&](int buf, int k0) {
    char* p = lds + buf * 20480;
    gload16(ga0 + k0, p + (w << 10));
    gload16(ga1 + k0, p + 4096 + (w << 10));
    gload16(gb0 + k0, p + 8192 + (w << 10));
    gload16(gb1 + k0, p + 12288 + (w << 10));
    gload16(gb2 + k0, p + 16384 + (w << 10));
  };
  stage(0, 0);
  #pragma unroll
  for (int k = 0; k < 4; ++k) {
    int cur = k & 1;
    if (k + 1 < 4) {
      stage(cur ^ 1, (k + 1) << 6);
      asm volatile("s_waitcnt vmcnt(5)" ::: "memory");
    } else {
      asm volatile("s_waitcnt vmcnt(0)" ::: "memory");
    }
    __builtin_amdgcn_s_barrier();
    char* p = lds + cur * 20480;
    #pragma unroll
    for (int ks = 0; ks < 2; ++ks) {
      int cb = (ks * 64 + fk) ^ fsw;
      short8v af = *(const short8v*)(p + arow + cb);
      #pragma unroll
      for (int n = 0; n < 6; ++n) {
        short8v bf = *(const short8v*)(p + 8192 + (n * 16 + fr) * 128 + cb);
        acc[n] = __builtin_amdgcn_mfma_f32_16x16x32_bf16(af, bf, acc[n], 0, 0, 0);
      }
    }
    __builtin_amdgcn_s_barrier();
  }

  int rb = bm + w * 16 + ((lane >> 4) << 2);
  #pragma unroll
  for (int j = 0; j < 4; ++j) {
    int r = rb + j;
    if (r >= M) break;
    #pragma unroll
    for (int n = 0; n < 6; ++n)
      atomicAdd(C + (size_t)r * 96 + n * 16 + fr, acc[n][j]);
  }
}

// ---------------- im2col -> bf16 patches ----------------
__global__ void im2col_k(const float* __restrict__ x, ushort* __restrict__ patches) {
  int idx = blockIdx.x * 256 + threadIdx.x;
  if (idx >= BATCH * NP * 768) return;
  int col = idx % 768, row = idx / 768;
  int b = row / NP, p = row % NP;
  int ph = p / 24, pw = p % 24;
  int c = col >> 8, r = col & 255, kh = r >> 4, kw = r & 15;
  patches[idx] = f2bf(x[(((size_t)(b * 3 + c) * 384) + ph * 16 + kh) * 384 + pw * 16 + kw]);
}

// ---------------- cls token row ----------------
__global__ void cls_k(const float* __restrict__ cls, const float* __restrict__ pos,
                      float* __restrict__ out) {
  int n = blockIdx.x * 256 + threadIdx.x;
  if (n >= DM) return;
  float v = cls[n] + pos[n];
  out[n] = v;
  out[(size_t)LSEQ * DM + n] = v;
}

// ---------------- LayerNorm -> bf16 (also zeroes this row's dbl slice) --------
__global__ __launch_bounds__(256) void ln_k(const float* __restrict__ tok,
    const float* __restrict__ w, const float* __restrict__ bsh,
    ushort* __restrict__ h, float* __restrict__ dbl0) {
  int row = blockIdx.x;
  const float* xr = tok + (size_t)row * DM;
  int tid = threadIdx.x;
  if (tid < 96) dbl0[(size_t)row * 96 + tid] = 0.f;
  float v[4];
  #pragma unroll
  for (int i = 0; i < 4; ++i) v[i] = xr[tid + 256 * i];
  float s = v[0] + v[1] + v[2] + v[3];
  float s2 = v[0] * v[0] + v[1] * v[1] + v[2] * v[2] + v[3] * v[3];
  #pragma unroll
  for (int off = 32; off; off >>= 1) { s += __shfl_xor(s, off); s2 += __shfl_xor(s2, off); }
  __shared__ float ps[4], ps2[4];
  if ((tid & 63) == 0) { ps[tid >> 6] = s; ps2[tid >> 6] = s2; }
  __syncthreads();
  s = ps[0] + ps[1] + ps[2] + ps[3];
  s2 = ps2[0] + ps2[1] + ps2[2] + ps2[3];
  float mean = s * (1.f / DM);
  float var = s2 * (1.f / DM) - mean * mean;
  float inv = rsqrtf(var + 1e-5f);
  #pragma unroll
  for (int i = 0; i < 4; ++i) {
    int c = tid + 256 * i;
    h[(size_t)row * DM + c] = f2bf((v[i] - mean) * inv * w[c] + bsh[c]);
  }
}

// ------- causal depthwise conv + silu -> bf16, 2 channels/thread (uint-packed) -------
__global__ void conv_silu_k(const ushort* __restrict__ xc, const float* __restrict__ cw,
                            const float* __restrict__ cb, ushort* __restrict__ ubf) {
  int idx = blockIdx.x * 256 + threadIdx.x;
  if (idx >= MROWS * (DI / 2)) return;
  int d2 = idx & (DI / 2 - 1);
  int ro = idx >> 10;
  int l = ro % LSEQ;
  int d = d2 << 1;
  float a0 = cb[d], a1 = cb[d + 1];
  const uint* xrow = (const uint*)xc + d2;
  float2 w0 = *(const float2*)(cw + d * 4);
  float2 w1 = *(const float2*)(cw + d * 4 + 2);
  float2 w2 = *(const float2*)(cw + (d + 1) * 4);
  float2 w3 = *(const float2*)(cw + (d + 1) * 4 + 2);
  float wA[4] = {w0.x, w0.y, w1.x, w1.y};
  float wB[4] = {w2.x, w2.y, w3.x, w3.y};
  #pragma unroll
  for (int k = 0; k < 4; ++k) {
    int ll = l - 3 + k;
    if (ll >= 0) {
      uint pr = xrow[(size_t)(ro - 3 + k) * (DI / 2)];
      a0 += bf2f((ushort)(pr & 0xFFFFu)) * wA[k];
      a1 += bf2f((ushort)(pr >> 16)) * wB[k];
    }
  }
  uint outp = (uint)f2bf(a0 / (1.f + __expf(-a0))) |
              ((uint)f2bf(a1 / (1.f + __expf(-a1))) << 16);
  ((uint*)ubf)[idx] = outp;
}

// ---------------- chunked selective scan (NC=32, LC=19, Ap/He bf16) ----------------
__global__ __launch_bounds__(256) void scan1_k(
    const ushort* __restrict__ dt, const ushort* __restrict__ ubf,
    const float* __restrict__ dbl, const float* __restrict__ alog,
    ushort* __restrict__ Ap, ushort* __restrict__ He)
{
  int d = blockIdx.x * 256 + threadIdx.x;
  int b = blockIdx.y, c = blockIdx.z;
  int t0 = c * LC, t1 = t0 + LC; if (t1 > LSEQ) t1 = LSEQ;
  float Ad[DSTATE], h[DSTATE];
  #pragma unroll
  for (int s = 0; s < DSTATE; ++s) {
    Ad[s] = -__expf(alog[d * DSTATE + s]); h[s] = 0.f;
  }
  bool fast = true;
  #pragma unroll
  for (int s = 1; s < DSTATE; ++s)
    fast = fast && (fabsf(Ad[s] - (s + 1) * Ad[0]) <= 1e-5f * (s + 1) * fabsf(Ad[0]));
  size_t o = (((size_t)(b * NC + c)) * DI + d) * DSTATE;
  if (fast) {
    float a1 = Ad[0] * LOG2E;
    float p = 1.f;
    for (int t = t0; t < t1; ++t) {
      size_t ro = (size_t)b * LSEQ + t;
      float dtv = bf2f(dt[ro * DI + d]);
      float du = dtv * bf2f(ubf[ro * DI + d]);
      const float* r = dbl + ro * 96;
      float e1 = exp2f(dtv * a1);
      p *= e1;
      float e = e1;
      #pragma unroll
      for (int s = 0; s < DSTATE; ++s) {
        h[s] = e * h[s] + du * r[64 + s];
        e *= e1;
      }
    }
    float pw = p;
    #pragma unroll
    for (int s = 0; s < DSTATE; ++s) {
      Ap[o + s] = f2bf(pw); He[o + s] = f2bf(h[s]);
      pw *= p;
    }
  } else {
    float ap[DSTATE];
    #pragma unroll
    for (int s = 0; s < DSTATE; ++s) ap[s] = 1.f;
    for (int t = t0; t < t1; ++t) {
      size_t ro = (size_t)b * LSEQ + t;
      float dtv = bf2f(dt[ro * DI + d]);
      float du = dtv * bf2f(ubf[ro * DI + d]);
      const float* r = dbl + ro * 96;
      #pragma unroll
      for (int s = 0; s < DSTATE; ++s) {
        float e = __expf(dtv * Ad[s]);
        h[s] = e * h[s] + du * r[64 + s];
        ap[s] *= e;
      }
    }
    #pragma unroll
    for (int s = 0; s < DSTATE; ++s) { Ap[o + s] = f2bf(ap[s]); He[o + s] = f2bf(h[s]); }
  }
}

__global__ __launch_bounds__(256) void scan2_k(
    ushort* __restrict__ Ap, const ushort* __restrict__ He)
{
  int ds = blockIdx.x * 256 + threadIdx.x;
  int b = blockIdx.y;
  float h = 0.f;
  #pragma unroll
  for (int g = 0; g < NC; g += 8) {
    float apg[8], heg[8];
    #pragma unroll
    for (int j = 0; j < 8; ++j) {
      size_t oo = ((size_t)(b * NC + g + j)) * DI * DSTATE + ds;
      apg[j] = bf2f(Ap[oo]); heg[j] = bf2f(He[oo]);
    }
    #pragma unroll
    for (int j = 0; j < 8; ++j) {
      size_t oo = ((size_t)(b * NC + g + j)) * DI * DSTATE + ds;
      Ap[oo] = f2bf(h);
      h = apg[j] * h + heg[j];
    }
  }
}

__global__ __launch_bounds__(256) void scan3_k(
    const ushort* __restrict__ dt, const ushort* __restrict__ ubf,
    const float* __restrict__ dbl, const ushort* __restrict__ zbf,
    const float* __restrict__ alog, const float* __restrict__ dsk,
    const ushort* __restrict__ H0, ushort* __restrict__ y)
{
  int d = blockIdx.x * 256 + threadIdx.x;
  int b = blockIdx.y, c = blockIdx.z;
  int t0 = c * LC, t1 = t0 + LC; if (t1 > LSEQ) t1 = LSEQ;
  float Ad[DSTATE], h[DSTATE];
  size_t o = (((size_t)(b * NC + c)) * DI + d) * DSTATE;
  #pragma unroll
  for (int s = 0; s < DSTATE; ++s) {
    Ad[s] = -__expf(alog[d * DSTATE + s]);
    h[s] = bf2f(H0[o + s]);
  }
  bool fast = true;
  #pragma unroll
  for (int s = 1; s < DSTATE; ++s)
    fast = fast && (fabsf(Ad[s] - (s + 1) * Ad[0]) <= 1e-5f * (s + 1) * fabsf(Ad[0]));
  float Dv = dsk[d];
  if (fast) {
    float a1 = Ad[0] * LOG2E;
    for (int t = t0; t < t1; ++t) {
      size_t ro = (size_t)b * LSEQ + t;
      float dtv = bf2f(dt[ro * DI + d]);
      float uv = bf2f(ubf[ro * DI + d]);
      float du = dtv * uv;
      const float* r = dbl + ro * 96;
      float e1 = exp2f(dtv * a1);
      float e = e1;
      float yv = 0.f;
      #pragma unroll
      for (int s = 0; s < DSTATE; ++s) {
        h[s] = e * h[s] + du * r[64 + s];
        yv += h[s] * r[80 + s];
        e *= e1;
      }
      float z = bf2f(zbf[ro * DI + d]);
      y[ro * DI + d] = f2bf((yv + Dv * uv) * (z / (1.f + __expf(-z))));
    }
  } else {
    for (int t = t0; t < t1; ++t) {
      size_t ro = (size_t)b * LSEQ + t;
      float dtv = bf2f(dt[ro * DI + d]);
      float uv = bf2f(ubf[ro * DI + d]);
      float du = dtv * uv;
      const float* r = dbl + ro * 96;
      float yv = 0.f;
      #pragma unroll
      for (int s = 0; s < DSTATE; ++s) {
        h[s] = __expf(dtv * Ad[s]) * h[s] + du * r[64 + s];
        yv += h[s] * r[80 + s];
      }
      float z = bf2f(zbf[ro * DI + d]);
      y[ro * DI + d] = f2bf((yv + Dv * uv) * (z / (1.f + __expf(-z))));
    }
  }
}

extern "C" void kernel_launch(void* const* d_in, const int* in_sizes, int n_in,
                              void* d_out, int out_size, void* d_ws, size_t ws_size,
                              hipStream_t stream) {
  const float* x         = (const float*)d_in[0];
  const float* patch_w   = (const float*)d_in[1];
  const float* patch_b   = (const float*)d_in[2];
  const float* cls_token = (const float*)d_in[3];
  const float* pos_embed = (const float*)d_in[4];
  const float* ln_w      = (const float*)d_in[5];
  const float* ln_b      = (const float*)d_in[6];
  const float* in_proj_w = (const float*)d_in[7];
  const float* conv_w    = (const float*)d_in[8];
  const float* conv_b    = (const float*)d_in[9];
  const float* x_proj_w  = (const float*)d_in[10];
  const float* dt_proj_w = (const float*)d_in[11];
  const float* dt_proj_b = (const float*)d_in[12];
  const float* A_log     = (const float*)d_in[13];
  const float* D_skip    = (const float*)d_in[14];
  const float* out_proj_w= (const float*)d_in[15];
  float* tok = (float*)d_out;

  char* base = (char*)d_ws;
  ushort* xc_bf  = (ushort*)(base);                 //  4,726,784
  ushort* z_bf   = (ushort*)(base + 4726784);       //  4,726,784
  ushort* u_bf   = (ushort*)(base + 9453568);       //  4,726,784
  float*  dbl    = (float*)(base + 14180352);       //    443,136
  ushort* dt_bf  = (ushort*)(base + 14623488);      //  4,726,784
  ushort* h_bf   = (ushort*)(base + 19350272);      //  2,363,392
  ushort* y_bf   = (ushort*)(base + 21713664);      //  4,726,784
  ushort* Ap     = (ushort*)(base + 26440448);      //  4,194,304
  ushort* He     = (ushort*)(base + 30634752);      //  4,194,304
  ushort* wpatch = (ushort*)(base + 34829056);      //  1,572,864
  ushort* wxp    = (ushort*)(base + 36401920);      //  9,437,184
  ushort* wdt    = (ushort*)(base + 45839104);      //  6,291,456 (end ~52MB)
  ushort* patches= (ushort*)u_bf;                   // alias, pre-layer only

  // ---- one-time conversion: ONLY patch/xproj/dt weights (in/out read fp32 direct) ----
  f2bf_all_k<<<F2BF_BLOCKS, 256, 0, stream>>>(patch_w, x_proj_w, dt_proj_w,
                                              wpatch, wxp, wdt);

  // ---- patch embed (bf16 MFMA) + pos ----
  im2col_k<<<(BATCH * NP * 768 + 255) / 256, 256, 0, stream>>>(x, patches);
  {
    dim3 gp(DM / 128, (BATCH * NP) / 64);
    gemm64<0, 0, 3><<<gp, 256, 0, stream>>>(patches, 768, wpatch, 768, tok, DM,
                                            BATCH * NP, DM, 768, patch_b, pos_embed,
                                            nullptr, nullptr);
  }
  cls_k<<<(DM + 255) / 256, 256, 0, stream>>>(cls_token, pos_embed, tok);

  // ---- 24 mamba layers ----
  for (int l = 0; l < NLAYERS; ++l) {
    ln_k<<<MROWS, 256, 0, stream>>>(tok, ln_w + l * DM, ln_b + l * DM, h_bf, dbl);

    {
      dim3 g1(2 * DI / 128, (MROWS + 63) / 64);
      gemm64<0, 1, 4><<<g1, 256, 0, stream>>>(h_bf, DM, in_proj_w + (size_t)l * 2 * DI * DM, DM,
                                              nullptr, 0, MROWS, 2 * DI, DM,
                                              nullptr, nullptr, xc_bf, z_bf);
    }

    conv_silu_k<<<(MROWS * (DI / 2) + 255) / 256, 256, 0, stream>>>(
        xc_bf, conv_w + (size_t)l * DI * 4, conv_b + (size_t)l * DI, u_bf);

    {
      dim3 g2(8, (MROWS + 63) / 64);
      xproj_k<<<g2, 256, 0, stream>>>(u_bf, wxp + (size_t)l * 96 * DI, dbl, MROWS);
    }

    {
      dim3 g3(DI / 128, (MROWS + 63) / 64);
      gemm64<1, 0, 5><<<g3, 256, 0, stream>>>(dbl, 96, wdt + (size_t)l * DI * DTR, DTR,
                                              nullptr, 0, MROWS, DI, DTR,
                                              dt_proj_b + (size_t)l * DI, nullptr, dt_bf, nullptr);
    }

    {
      dim3 gs(DI / 256, BATCH, NC);
      scan1_k<<<gs, 256, 0, stream>>>(dt_bf, u_bf, dbl,
                                      A_log + (size_t)l * DI * DSTATE, Ap, He);
      dim3 gs2(DI * DSTATE / 256, BATCH);
      scan2_k<<<gs2, 256, 0, stream>>>(Ap, He);
      scan3_k<<<gs, 256, 0, stream>>>(dt_bf, u_bf, dbl, z_bf,
                                      A_log + (size_t)l * DI * DSTATE, D_skip + (size_t)l * DI,
                                      Ap, y_bf);
    }

    {
      dim3 g4(DM / 128, (MROWS + 63) / 64);
      gemm64<0, 1, 1><<<g4, 256, 0, stream>>>(y_bf, DI, out_proj_w + (size_t)l * DM * DI, DI,
                                              tok, DM, MROWS, DM, DI, nullptr, nullptr,
                                              nullptr, nullptr);
    }
  }
}

// Round 17
// 2896.871 us; speedup vs baseline: 1.5777x; 1.5777x over previous
//
#include <hip/hip_runtime.h>
#include <hip/hip_bf16.h>
#include <math.h>

#define BATCH 2
#define LSEQ 577
#define DM 1024
#define DI 2048
#define DSTATE 16
#define DTR 64
#define NLAYERS 24
#define NP 576
#define MROWS 1154
#define NC 32
#define LC 19
#define LOG2E 1.4426950408889634f

typedef __attribute__((ext_vector_type(8))) short short8v;
typedef __attribute__((ext_vector_type(4))) float f32x4;

__device__ __forceinline__ ushort f2bf(float f) {
  unsigned int b = __float_as_uint(f);
  return (ushort)((b + 0x7FFFu + ((b >> 16) & 1u)) >> 16);
}
__device__ __forceinline__ float bf2f(ushort u) {
  return __uint_as_float(((unsigned int)u) << 16);
}
__device__ __forceinline__ void gload16(const void* g, void* l) {
  __builtin_amdgcn_global_load_lds(
      (const __attribute__((address_space(1))) unsigned int*)g,
      (__attribute__((address_space(3))) unsigned int*)l, 16, 0, 0);
}
__device__ __forceinline__ void cvt16(const float* g, char* ldsrow, int bb, int bswz) {
  float4 v0 = *(const float4*)(g);
  float4 v1 = *(const float4*)(g + 4);
  float4 v2 = *(const float4*)(g + 8);
  float4 v3 = *(const float4*)(g + 12);
  short8v c0 = {(short)f2bf(v0.x), (short)f2bf(v0.y), (short)f2bf(v0.z), (short)f2bf(v0.w),
                (short)f2bf(v1.x), (short)f2bf(v1.y), (short)f2bf(v1.z), (short)f2bf(v1.w)};
  short8v c1 = {(short)f2bf(v2.x), (short)f2bf(v2.y), (short)f2bf(v2.z), (short)f2bf(v2.w),
                (short)f2bf(v3.x), (short)f2bf(v3.y), (short)f2bf(v3.z), (short)f2bf(v3.w)};
  *(short8v*)(ldsrow + (bb ^ bswz)) = c0;
  *(short8v*)(ldsrow + ((bb + 16) ^ bswz)) = c1;
}

// ---------------- fused fp32 -> bf16 weight conversion (branch-free blocks) ----------
#define SEG0 786432u
#define SEG1 4718592u
#define SEG2 3145728u
#define SEG3 50331648u
#define SEG4 100663296u
#define CUM1 (SEG0)
#define CUM2 (CUM1+SEG1)
#define CUM3 (CUM2+SEG2)
#define CUM4 (CUM3+SEG3)
#define CUMT (CUM4+SEG4)
#define F2BF_BLOCKS (CUMT/4096)

__global__ void f2bf_all_k(const float* __restrict__ i0, const float* __restrict__ i1,
                           const float* __restrict__ i2, const float* __restrict__ i3,
                           const float* __restrict__ i4,
                           ushort* __restrict__ o0, ushort* __restrict__ o1,
                           ushort* __restrict__ o2, ushort* __restrict__ o3,
                           ushort* __restrict__ o4) {
  size_t base = (size_t)blockIdx.x * 4096;
  const float* in; ushort* out; size_t off;
  if (base < CUM1)      { in = i0; out = o0; off = base; }
  else if (base < CUM2) { in = i1; out = o1; off = base - CUM1; }
  else if (base < CUM3) { in = i2; out = o2; off = base - CUM2; }
  else if (base < CUM4) { in = i3; out = o3; off = base - CUM3; }
  else                  { in = i4; out = o4; off = base - CUM4; }
  size_t p = off + threadIdx.x * 4;
  #pragma unroll
  for (int j = 0; j < 4; ++j) {
    float4 v = *(const float4*)(in + p + j * 1024);
    ushort4 o;
    o.x = f2bf(v.x); o.y = f2bf(v.y); o.z = f2bf(v.z); o.w = f2bf(v.w);
    *(ushort4*)(out + p + j * 1024) = o;
  }
}

// ======================= 64x128 bf16 MFMA GEMM =======================
template<int AF32, int MODE>
__global__ __launch_bounds__(256) void gemm64(
    const void* __restrict__ Ap_, int lda,
    const ushort* __restrict__ Bw, int ldb,
    float* __restrict__ C, int ldc,
    int M, int N, int K,
    const float* __restrict__ bias, const float* __restrict__ pos,
    ushort* __restrict__ o16a, ushort* __restrict__ o16b)
{
  __shared__ char lds[AF32 ? 24576 : 49152];
  int tid = threadIdx.x;
  int lane = tid & 63, w = tid >> 6;

  int nwg = gridDim.x * gridDim.y;
  int f = blockIdx.y * gridDim.x + blockIdx.x;
  int L = (f & 7) * (nwg >> 3) + (f >> 3);
  int bx = L % gridDim.x, by = L / gridDim.x;
  int bm = by * 64, bn = bx * 128;

  int srow = tid >> 3;
  int scol = ((tid & 7) ^ (srow & 7)) << 3;

  const ushort* gb0 = Bw + (size_t)(bn + srow) * ldb + scol;
  const ushort* gb1 = Bw + (size_t)(bn + 32 + srow) * ldb + scol;
  const ushort* gb2 = Bw + (size_t)(bn + 64 + srow) * ldb + scol;
  const ushort* gb3 = Bw + (size_t)(bn + 96 + srow) * ldb + scol;

  const ushort* ga0 = nullptr; const ushort* ga1 = nullptr;
  const float* gAf = nullptr; char* ldsArow = nullptr; int bb = 0, bswz = 0;
  if (!AF32) {
    const ushort* Abf = (const ushort*)Ap_;
    int ra0 = bm + srow;      if (ra0 > M - 1) ra0 = M - 1;
    int ra1 = bm + 32 + srow; if (ra1 > M - 1) ra1 = M - 1;
    ga0 = Abf + (size_t)ra0 * lda + scol;
    ga1 = Abf + (size_t)ra1 * lda + scol;
  } else {
    int brow = tid >> 2;
    int be0 = (tid & 3) << 4;
    bb = be0 << 1; bswz = (brow & 7) << 4;
    int raf = bm + brow; if (raf > M - 1) raf = M - 1;
    gAf = (const float*)Ap_ + (size_t)raf * lda + be0;
    ldsArow = lds + brow * 128;
  }

  int wr = w >> 1, wc = w & 1;
  int fr = lane & 15;
  int fsw = (fr & 7) << 4;
  int fk = (lane >> 4) << 4;

  f32x4 acc[2][4];
  #pragma unroll
  for (int m = 0; m < 2; ++m)
    #pragma unroll
    for (int n = 0; n < 4; ++n) acc[m][n] = (f32x4){0.f, 0.f, 0.f, 0.f};

  if constexpr (!AF32) {
    auto stage = [&](int buf, int k0) {
      char* p = lds + buf * 24576;
      gload16(ga0 + k0, p + (w << 10));
      gload16(ga1 + k0, p + 4096 + (w << 10));
      gload16(gb0 + k0, p + 8192 + (w << 10));
      gload16(gb1 + k0, p + 12288 + (w << 10));
      gload16(gb2 + k0, p + 16384 + (w << 10));
      gload16(gb3 + k0, p + 20480 + (w << 10));
    };
    int nk = K >> 6;
    stage(0, 0);
    for (int k = 0; k < nk; ++k) {
      int cur = k & 1;
      if (k + 1 < nk) {
        stage(cur ^ 1, (k + 1) << 6);
        asm volatile("s_waitcnt vmcnt(6)" ::: "memory");
      } else {
        asm volatile("s_waitcnt vmcnt(0)" ::: "memory");
      }
      __builtin_amdgcn_s_barrier();
      char* p = lds + cur * 24576;
      #pragma unroll
      for (int ks = 0; ks < 2; ++ks) {
        int cb = (ks * 64 + fk) ^ fsw;
        short8v af[2], bf[4];
        #pragma unroll
        for (int m = 0; m < 2; ++m)
          af[m] = *(const short8v*)(p + (wr * 32 + m * 16 + fr) * 128 + cb);
        #pragma unroll
        for (int n = 0; n < 4; ++n)
          bf[n] = *(const short8v*)(p + 8192 + (wc * 64 + n * 16 + fr) * 128 + cb);
        #pragma unroll
        for (int m = 0; m < 2; ++m)
          #pragma unroll
          for (int n = 0; n < 4; ++n)
            acc[m][n] = __builtin_amdgcn_mfma_f32_16x16x32_bf16(af[m], bf[n], acc[m][n], 0, 0, 0);
      }
      __builtin_amdgcn_s_barrier();
    }
  } else {
    for (int k0 = 0; k0 < K; k0 += 64) {
      cvt16(gAf + k0, ldsArow, bb, bswz);
      gload16(gb0 + k0, lds + 8192 + (w << 10));
      gload16(gb1 + k0, lds + 12288 + (w << 10));
      gload16(gb2 + k0, lds + 16384 + (w << 10));
      gload16(gb3 + k0, lds + 20480 + (w << 10));
      __syncthreads();
      #pragma unroll
      for (int ks = 0; ks < 2; ++ks) {
        int cb = (ks * 64 + fk) ^ fsw;
        short8v af[2], bf[4];
        #pragma unroll
        for (int m = 0; m < 2; ++m)
          af[m] = *(const short8v*)(lds + (wr * 32 + m * 16 + fr) * 128 + cb);
        #pragma unroll
        for (int n = 0; n < 4; ++n)
          bf[n] = *(const short8v*)(lds + 8192 + (wc * 64 + n * 16 + fr) * 128 + cb);
        #pragma unroll
        for (int m = 0; m < 2; ++m)
          #pragma unroll
          for (int n = 0; n < 4; ++n)
            acc[m][n] = __builtin_amdgcn_mfma_f32_16x16x32_bf16(af[m], bf[n], acc[m][n], 0, 0, 0);
      }
      __syncthreads();
    }
  }

  #pragma unroll
  for (int m = 0; m < 2; ++m) {
    int rb = bm + wr * 32 + m * 16 + ((lane >> 4) << 2);
    #pragma unroll
    for (int j = 0; j < 4; ++j) {
      int r = rb + j;
      if (r >= M) break;
      #pragma unroll
      for (int n2 = 0; n2 < 4; ++n2) {
        int n = bn + wc * 64 + n2 * 16 + fr;
        float v = acc[m][n2][j];
        if (MODE == 1) {
          C[(size_t)r * ldc + n] += v;
        } else if (MODE == 3) {
          int b = r / NP, p = r % NP;
          C[((size_t)(b * LSEQ + 1 + p)) * ldc + n] = v + bias[n] + pos[(size_t)(1 + p) * ldc + n];
        } else if (MODE == 4) {
          if (n < DI) o16a[(size_t)r * DI + n] = f2bf(v);
          else        o16b[(size_t)r * DI + n - DI] = f2bf(v);
        } else {
          float t = v + bias[n];
          o16a[(size_t)r * N + n] = f2bf((t > 20.f) ? t : log1pf(__expf(t)));
        }
      }
    }
  }
}

// ======================= x_proj split-K MFMA (dbuf + counted vmcnt) ==========
__global__ __launch_bounds__(256) void xproj_k(
    const ushort* __restrict__ A, const ushort* __restrict__ W,
    float* __restrict__ C, int M)
{
  __shared__ char lds[40960];
  int tid = threadIdx.x;
  int lane = tid & 63, w = tid >> 6;
  int bm = blockIdx.y * 64;
  int kbase = blockIdx.x * 256;

  int srow = tid >> 3;
  int scol = ((tid & 7) ^ (srow & 7)) << 3;
  int ra0 = bm + srow;      if (ra0 > M - 1) ra0 = M - 1;
  int ra1 = bm + 32 + srow; if (ra1 > M - 1) ra1 = M - 1;
  const ushort* ga0 = A + (size_t)ra0 * DI + kbase + scol;
  const ushort* ga1 = A + (size_t)ra1 * DI + kbase + scol;
  const ushort* gb0 = W + (size_t)(srow)      * DI + kbase + scol;
  const ushort* gb1 = W + (size_t)(srow + 32) * DI + kbase + scol;
  const ushort* gb2 = W + (size_t)(srow + 64) * DI + kbase + scol;

  int fr = lane & 15;
  int fsw = (fr & 7) << 4;
  int fk = (lane >> 4) << 4;
  int arow = (w * 16 + fr) * 128;

  f32x4 acc[6];
  #pragma unroll
  for (int n = 0; n < 6; ++n) acc[n] = (f32x4){0.f, 0.f, 0.f, 0.f};

  auto stage = [&](int buf, int k0) {
    char* p = lds + buf * 20480;
    gload16(ga0 + k0, p + (w << 10));
    gload16(ga1 + k0, p + 4096 + (w << 10));
    gload16(gb0 + k0, p + 8192 + (w << 10));
    gload16(gb1 + k0, p + 12288 + (w << 10));
    gload16(gb2 + k0, p + 16384 + (w << 10));
  };
  stage(0, 0);
  #pragma unroll
  for (int k = 0; k < 4; ++k) {
    int cur = k & 1;
    if (k + 1 < 4) {
      stage(cur ^ 1, (k + 1) << 6);
      asm volatile("s_waitcnt vmcnt(5)" ::: "memory");
    } else {
      asm volatile("s_waitcnt vmcnt(0)" ::: "memory");
    }
    __builtin_amdgcn_s_barrier();
    char* p = lds + cur * 20480;
    #pragma unroll
    for (int ks = 0; ks < 2; ++ks) {
      int cb = (ks * 64 + fk) ^ fsw;
      short8v af = *(const short8v*)(p + arow + cb);
      #pragma unroll
      for (int n = 0; n < 6; ++n) {
        short8v bf = *(const short8v*)(p + 8192 + (n * 16 + fr) * 128 + cb);
        acc[n] = __builtin_amdgcn_mfma_f32_16x16x32_bf16(af, bf, acc[n], 0, 0, 0);
      }
    }
    __builtin_amdgcn_s_barrier();
  }

  int rb = bm + w * 16 + ((lane >> 4) << 2);
  #pragma unroll
  for (int j = 0; j < 4; ++j) {
    int r = rb + j;
    if (r >= M) break;
    #pragma unroll
    for (int n = 0; n < 6; ++n)
      atomicAdd(C + (size_t)r * 96 + n * 16 + fr, acc[n][j]);
  }
}

// ---------------- im2col -> bf16 patches ----------------
__global__ void im2col_k(const float* __restrict__ x, ushort* __restrict__ patches) {
  int idx = blockIdx.x * 256 + threadIdx.x;
  if (idx >= BATCH * NP * 768) return;
  int col = idx % 768, row = idx / 768;
  int b = row / NP, p = row % NP;
  int ph = p / 24, pw = p % 24;
  int c = col >> 8, r = col & 255, kh = r >> 4, kw = r & 15;
  patches[idx] = f2bf(x[(((size_t)(b * 3 + c) * 384) + ph * 16 + kh) * 384 + pw * 16 + kw]);
}

// ---------------- cls token row ----------------
__global__ void cls_k(const float* __restrict__ cls, const float* __restrict__ pos,
                      float* __restrict__ out) {
  int n = blockIdx.x * 256 + threadIdx.x;
  if (n >= DM) return;
  float v = cls[n] + pos[n];
  out[n] = v;
  out[(size_t)LSEQ * DM + n] = v;
}

// ---------------- LayerNorm -> bf16 (also zeroes this row's dbl slice) --------
__global__ __launch_bounds__(256) void ln_k(const float* __restrict__ tok,
    const float* __restrict__ w, const float* __restrict__ bsh,
    ushort* __restrict__ h, float* __restrict__ dbl0) {
  int row = blockIdx.x;
  const float* xr = tok + (size_t)row * DM;
  int tid = threadIdx.x;
  if (tid < 96) dbl0[(size_t)row * 96 + tid] = 0.f;
  float v[4];
  #pragma unroll
  for (int i = 0; i < 4; ++i) v[i] = xr[tid + 256 * i];
  float s = v[0] + v[1] + v[2] + v[3];
  float s2 = v[0] * v[0] + v[1] * v[1] + v[2] * v[2] + v[3] * v[3];
  #pragma unroll
  for (int off = 32; off; off >>= 1) { s += __shfl_xor(s, off); s2 += __shfl_xor(s2, off); }
  __shared__ float ps[4], ps2[4];
  if ((tid & 63) == 0) { ps[tid >> 6] = s; ps2[tid >> 6] = s2; }
  __syncthreads();
  s = ps[0] + ps[1] + ps[2] + ps[3];
  s2 = ps2[0] + ps2[1] + ps2[2] + ps2[3];
  float mean = s * (1.f / DM);
  float var = s2 * (1.f / DM) - mean * mean;
  float inv = rsqrtf(var + 1e-5f);
  #pragma unroll
  for (int i = 0; i < 4; ++i) {
    int c = tid + 256 * i;
    h[(size_t)row * DM + c] = f2bf((v[i] - mean) * inv * w[c] + bsh[c]);
  }
}

// ------- causal depthwise conv + silu -> bf16, 2 channels/thread (uint-packed) -------
__global__ void conv_silu_k(const ushort* __restrict__ xc, const float* __restrict__ cw,
                            const float* __restrict__ cb, ushort* __restrict__ ubf) {
  int idx = blockIdx.x * 256 + threadIdx.x;
  if (idx >= MROWS * (DI / 2)) return;
  int d2 = idx & (DI / 2 - 1);
  int ro = idx >> 10;
  int l = ro % LSEQ;
  int d = d2 << 1;
  float a0 = cb[d], a1 = cb[d + 1];
  const uint* xrow = (const uint*)xc + d2;
  float2 w0 = *(const float2*)(cw + d * 4);
  float2 w1 = *(const float2*)(cw + d * 4 + 2);
  float2 w2 = *(const float2*)(cw + (d + 1) * 4);
  float2 w3 = *(const float2*)(cw + (d + 1) * 4 + 2);
  float wA[4] = {w0.x, w0.y, w1.x, w1.y};
  float wB[4] = {w2.x, w2.y, w3.x, w3.y};
  #pragma unroll
  for (int k = 0; k < 4; ++k) {
    int ll = l - 3 + k;
    if (ll >= 0) {
      uint pr = xrow[(size_t)(ro - 3 + k) * (DI / 2)];
      a0 += bf2f((ushort)(pr & 0xFFFFu)) * wA[k];
      a1 += bf2f((ushort)(pr >> 16)) * wB[k];
    }
  }
  uint outp = (uint)f2bf(a0 / (1.f + __expf(-a0))) |
              ((uint)f2bf(a1 / (1.f + __expf(-a1))) << 16);
  ((uint*)ubf)[idx] = outp;
}

// ---------------- chunked selective scan (NC=32, LC=19, Ap/He bf16) ----------------
__global__ __launch_bounds__(256) void scan1_k(
    const ushort* __restrict__ dt, const ushort* __restrict__ ubf,
    const float* __restrict__ dbl, const float* __restrict__ alog,
    ushort* __restrict__ Ap, ushort* __restrict__ He)
{
  int d = blockIdx.x * 256 + threadIdx.x;
  int b = blockIdx.y, c = blockIdx.z;
  int t0 = c * LC, t1 = t0 + LC; if (t1 > LSEQ) t1 = LSEQ;
  float Ad[DSTATE], h[DSTATE];
  #pragma unroll
  for (int s = 0; s < DSTATE; ++s) {
    Ad[s] = -__expf(alog[d * DSTATE + s]); h[s] = 0.f;
  }
  bool fast = true;
  #pragma unroll
  for (int s = 1; s < DSTATE; ++s)
    fast = fast && (fabsf(Ad[s] - (s + 1) * Ad[0]) <= 1e-5f * (s + 1) * fabsf(Ad[0]));
  size_t o = (((size_t)(b * NC + c)) * DI + d) * DSTATE;
  if (fast) {
    float a1 = Ad[0] * LOG2E;
    float p = 1.f;
    for (int t = t0; t < t1; ++t) {
      size_t ro = (size_t)b * LSEQ + t;
      float dtv = bf2f(dt[ro * DI + d]);
      float du = dtv * bf2f(ubf[ro * DI + d]);
      const float* r = dbl + ro * 96;
      float e1 = exp2f(dtv * a1);
      p *= e1;
      float e = e1;
      #pragma unroll
      for (int s = 0; s < DSTATE; ++s) {
        h[s] = e * h[s] + du * r[64 + s];
        e *= e1;
      }
    }
    float pw = p;
    #pragma unroll
    for (int s = 0; s < DSTATE; ++s) {
      Ap[o + s] = f2bf(pw); He[o + s] = f2bf(h[s]);
      pw *= p;
    }
  } else {
    float ap[DSTATE];
    #pragma unroll
    for (int s = 0; s < DSTATE; ++s) ap[s] = 1.f;
    for (int t = t0; t < t1; ++t) {
      size_t ro = (size_t)b * LSEQ + t;
      float dtv = bf2f(dt[ro * DI + d]);
      float du = dtv * bf2f(ubf[ro * DI + d]);
      const float* r = dbl + ro * 96;
      #pragma unroll
      for (int s = 0; s < DSTATE; ++s) {
        float e = __expf(dtv * Ad[s]);
        h[s] = e * h[s] + du * r[64 + s];
        ap[s] *= e;
      }
    }
    #pragma unroll
    for (int s = 0; s < DSTATE; ++s) { Ap[o + s] = f2bf(ap[s]); He[o + s] = f2bf(h[s]); }
  }
}

__global__ __launch_bounds__(256) void scan2_k(
    ushort* __restrict__ Ap, const ushort* __restrict__ He)
{
  int ds = blockIdx.x * 256 + threadIdx.x;
  int b = blockIdx.y;
  float h = 0.f;
  #pragma unroll
  for (int g = 0; g < NC; g += 8) {
    float apg[8], heg[8];
    #pragma unroll
    for (int j = 0; j < 8; ++j) {
      size_t oo = ((size_t)(b * NC + g + j)) * DI * DSTATE + ds;
      apg[j] = bf2f(Ap[oo]); heg[j] = bf2f(He[oo]);
    }
    #pragma unroll
    for (int j = 0; j < 8; ++j) {
      size_t oo = ((size_t)(b * NC + g + j)) * DI * DSTATE + ds;
      Ap[oo] = f2bf(h);
      h = apg[j] * h + heg[j];
    }
  }
}

__global__ __launch_bounds__(256) void scan3_k(
    const ushort* __restrict__ dt, const ushort* __restrict__ ubf,
    const float* __restrict__ dbl, const ushort* __restrict__ zbf,
    const float* __restrict__ alog, const float* __restrict__ dsk,
    const ushort* __restrict__ H0, ushort* __restrict__ y)
{
  int d = blockIdx.x * 256 + threadIdx.x;
  int b = blockIdx.y, c = blockIdx.z;
  int t0 = c * LC, t1 = t0 + LC; if (t1 > LSEQ) t1 = LSEQ;
  float Ad[DSTATE], h[DSTATE];
  size_t o = (((size_t)(b * NC + c)) * DI + d) * DSTATE;
  #pragma unroll
  for (int s = 0; s < DSTATE; ++s) {
    Ad[s] = -__expf(alog[d * DSTATE + s]);
    h[s] = bf2f(H0[o + s]);
  }
  bool fast = true;
  #pragma unroll
  for (int s = 1; s < DSTATE; ++s)
    fast = fast && (fabsf(Ad[s] - (s + 1) * Ad[0]) <= 1e-5f * (s + 1) * fabsf(Ad[0]));
  float Dv = dsk[d];
  if (fast) {
    float a1 = Ad[0] * LOG2E;
    for (int t = t0; t < t1; ++t) {
      size_t ro = (size_t)b * LSEQ + t;
      float dtv = bf2f(dt[ro * DI + d]);
      float uv = bf2f(ubf[ro * DI + d]);
      float du = dtv * uv;
      const float* r = dbl + ro * 96;
      float e1 = exp2f(dtv * a1);
      float e = e1;
      float yv = 0.f;
      #pragma unroll
      for (int s = 0; s < DSTATE; ++s) {
        h[s] = e * h[s] + du * r[64 + s];
        yv += h[s] * r[80 + s];
        e *= e1;
      }
      float z = bf2f(zbf[ro * DI + d]);
      y[ro * DI + d] = f2bf((yv + Dv * uv) * (z / (1.f + __expf(-z))));
    }
  } else {
    for (int t = t0; t < t1; ++t) {
      size_t ro = (size_t)b * LSEQ + t;
      float dtv = bf2f(dt[ro * DI + d]);
      float uv = bf2f(ubf[ro * DI + d]);
      float du = dtv * uv;
      const float* r = dbl + ro * 96;
      float yv = 0.f;
      #pragma unroll
      for (int s = 0; s < DSTATE; ++s) {
        h[s] = __expf(dtv * Ad[s]) * h[s] + du * r[64 + s];
        yv += h[s] * r[80 + s];
      }
      float z = bf2f(zbf[ro * DI + d]);
      y[ro * DI + d] = f2bf((yv + Dv * uv) * (z / (1.f + __expf(-z))));
    }
  }
}

extern "C" void kernel_launch(void* const* d_in, const int* in_sizes, int n_in,
                              void* d_out, int out_size, void* d_ws, size_t ws_size,
                              hipStream_t stream) {
  const float* x         = (const float*)d_in[0];
  const float* patch_w   = (const float*)d_in[1];
  const float* patch_b   = (const float*)d_in[2];
  const float* cls_token = (const float*)d_in[3];
  const float* pos_embed = (const float*)d_in[4];
  const float* ln_w      = (const float*)d_in[5];
  const float* ln_b      = (const float*)d_in[6];
  const float* in_proj_w = (const float*)d_in[7];
  const float* conv_w    = (const float*)d_in[8];
  const float* conv_b    = (const float*)d_in[9];
  const float* x_proj_w  = (const float*)d_in[10];
  const float* dt_proj_w = (const float*)d_in[11];
  const float* dt_proj_b = (const float*)d_in[12];
  const float* A_log     = (const float*)d_in[13];
  const float* D_skip    = (const float*)d_in[14];
  const float* out_proj_w= (const float*)d_in[15];
  float* tok = (float*)d_out;

  char* base = (char*)d_ws;
  ushort* xc_bf  = (ushort*)(base);                 //  4,726,784
  ushort* z_bf   = (ushort*)(base + 4726784);       //  4,726,784
  ushort* u_bf   = (ushort*)(base + 9453568);       //  4,726,784
  float*  dbl    = (float*)(base + 14180352);       //    443,136
  ushort* dt_bf  = (ushort*)(base + 14623488);      //  4,726,784
  ushort* h_bf   = (ushort*)(base + 19350272);      //  2,363,392
  ushort* y_bf   = (ushort*)(base + 21713664);      //  4,726,784
  ushort* Ap     = (ushort*)(base + 26440448);      //  4,194,304
  ushort* He     = (ushort*)(base + 30634752);      //  4,194,304
  ushort* wpatch = (ushort*)(base + 34829056);      //  1,572,864
  ushort* wxp    = (ushort*)(base + 36401920);      //  9,437,184
  ushort* wdt    = (ushort*)(base + 45839104);      //  6,291,456
  ushort* wout   = (ushort*)(base + 52130560);      // 100,663,296
  ushort* win    = (ushort*)(base + 152793856);     // 201,326,592 (end ~354MB)
  ushort* patches= (ushort*)u_bf;                   // alias, pre-layer only

  // ---- one-time (per call) weight conversion to bf16, single branch-free launch ----
  f2bf_all_k<<<F2BF_BLOCKS, 256, 0, stream>>>(patch_w, x_proj_w, dt_proj_w, out_proj_w,
                                              in_proj_w, wpatch, wxp, wdt, wout, win);

  // ---- patch embed (bf16 MFMA) + pos ----
  im2col_k<<<(BATCH * NP * 768 + 255) / 256, 256, 0, stream>>>(x, patches);
  {
    dim3 gp(DM / 128, (BATCH * NP) / 64);
    gemm64<0, 3><<<gp, 256, 0, stream>>>(patches, 768, wpatch, 768, tok, DM,
                                         BATCH * NP, DM, 768, patch_b, pos_embed,
                                         nullptr, nullptr);
  }
  cls_k<<<(DM + 255) / 256, 256, 0, stream>>>(cls_token, pos_embed, tok);

  // ---- 24 mamba layers ----
  for (int l = 0; l < NLAYERS; ++l) {
    ln_k<<<MROWS, 256, 0, stream>>>(tok, ln_w + l * DM, ln_b + l * DM, h_bf, dbl);

    {
      dim3 g1(2 * DI / 128, (MROWS + 63) / 64);
      gemm64<0, 4><<<g1, 256, 0, stream>>>(h_bf, DM, win + (size_t)l * 2 * DI * DM, DM,
                                           nullptr, 0, MROWS, 2 * DI, DM,
                                           nullptr, nullptr, xc_bf, z_bf);
    }

    conv_silu_k<<<(MROWS * (DI / 2) + 255) / 256, 256, 0, stream>>>(
        xc_bf, conv_w + (size_t)l * DI * 4, conv_b + (size_t)l * DI, u_bf);

    {
      dim3 g2(8, (MROWS + 63) / 64);
      xproj_k<<<g2, 256, 0, stream>>>(u_bf, wxp + (size_t)l * 96 * DI, dbl, MROWS);
    }

    {
      dim3 g3(DI / 128, (MROWS + 63) / 64);
      gemm64<1, 5><<<g3, 256, 0, stream>>>(dbl, 96, wdt + (size_t)l * DI * DTR, DTR,
                                           nullptr, 0, MROWS, DI, DTR,
                                           dt_proj_b + (size_t)l * DI, nullptr, dt_bf, nullptr);
    }

    {
      dim3 gs(DI / 256, BATCH, NC);
      scan1_k<<<gs, 256, 0, stream>>>(dt_bf, u_bf, dbl,
                                      A_log + (size_t)l * DI * DSTATE, Ap, He);
      dim3 gs2(DI * DSTATE / 256, BATCH);
      scan2_k<<<gs2, 256, 0, stream>>>(Ap, He);
      scan3_k<<<gs, 256, 0, stream>>>(dt_bf, u_bf, dbl, z_bf,
                                      A_log + (size_t)l * DI * DSTATE, D_skip + (size_t)l * DI,
                                      Ap, y_bf);
    }

    {
      dim3 g4(DM / 128, (MROWS + 63) / 64);
      gemm64<0, 1><<<g4, 256, 0, stream>>>(y_bf, DI, wout + (size_t)l * DM * DI, DI,
                                           tok, DM, MROWS, DM, DI, nullptr, nullptr,
                                           nullptr, nullptr);
    }
  }
}